// Round 1
// baseline (151.260 us; speedup 1.0000x reference)
//
#include <hip/hip_runtime.h>
#include <hip/hip_bf16.h>

// Problem constants (from reference): B=4, Q=K=512, D=512, H=256
#define HH 256      // NUM_HIDDENS
#define DD 512      // QUERY_SIZE == KEY_SIZE
#define MM 2048     // B*Q == B*K flattened rows

typedef __bf16 bf16x8 __attribute__((ext_vector_type(8)));
typedef float floatx4 __attribute__((ext_vector_type(4)));

// ---------------------------------------------------------------------------
// Projection: P = X(2048x512) @ W(512x256), bf16 MFMA 16x16x32, one wave/block.
//   blockIdx.z==0: X=queries,W=W_q -> qp row-major [2048][256]
//   blockIdx.z==1: X=keys,   W=W_k -> kpt TRANSPOSED [256][2048]  (for coalesced
//                                     k-reads in the score kernel)
// Fragment layouts (HW-verified per guide):
//   A: lane holds A[m=lane&15][k=(lane>>4)*8 + j], j=0..7
//   B: lane holds B[k=(lane>>4)*8 + j][n=lane&15]
//   D: reg i holds D[row=(lane>>4)*4 + i][col=lane&15]
// ---------------------------------------------------------------------------
__global__ __launch_bounds__(64) void proj_kernel(
    const float* __restrict__ queries, const float* __restrict__ keys,
    const float* __restrict__ Wq, const float* __restrict__ Wk,
    float* __restrict__ qp, float* __restrict__ kpt)
{
  const int lane = threadIdx.x;
  const int quad = lane >> 4;
  const int r    = lane & 15;
  const int m0 = blockIdx.x * 16;   // row tile in [0,2048)
  const int n0 = blockIdx.y * 16;   // col tile in [0,256)
  const bool is_k = (blockIdx.z != 0);
  const float* __restrict__ X = is_k ? keys : queries;
  const float* __restrict__ W = is_k ? Wk : Wq;

  floatx4 acc = {0.f, 0.f, 0.f, 0.f};
  const float* arow = X + (m0 + r) * DD + quad * 8;
  const float* bcol = W + (quad * 8) * HH + n0 + r;

  for (int kk = 0; kk < DD; kk += 32) {
    float4 a0 = *(const float4*)(arow + kk);
    float4 a1 = *(const float4*)(arow + kk + 4);
    bf16x8 af, bfv;
    af[0] = (__bf16)a0.x; af[1] = (__bf16)a0.y;
    af[2] = (__bf16)a0.z; af[3] = (__bf16)a0.w;
    af[4] = (__bf16)a1.x; af[5] = (__bf16)a1.y;
    af[6] = (__bf16)a1.z; af[7] = (__bf16)a1.w;
    const float* bp = bcol + kk * HH;
#pragma unroll
    for (int j = 0; j < 8; ++j) bfv[j] = (__bf16)bp[j * HH];
    acc = __builtin_amdgcn_mfma_f32_16x16x32_bf16(af, bfv, acc, 0, 0, 0);
  }

  if (!is_k) {
#pragma unroll
    for (int i = 0; i < 4; ++i)
      qp[(m0 + quad * 4 + i) * HH + n0 + r] = acc[i];
  } else {
#pragma unroll
    for (int i = 0; i < 4; ++i)
      kpt[(n0 + r) * MM + (m0 + quad * 4 + i)] = acc[i];
  }
}

// ---------------------------------------------------------------------------
// Score: out[b,q,k] = sum_h wv[h] * tanh(qp[b,q,h] + kp[b,k,h])
// tanh(x) = 1 - 2/(exp2(2*log2e*x) + 1)   (stable at +-inf)
// thread t -> one k column, TQ=4 q rows. k-reads coalesced from kpt[h][:],
// q and wv reads wave-uniform (scalar-load path). No LDS at all.
// grid (K/256=2, Q/4=128, B=4), block 256 -> 4096 waves = 4/SIMD.
// ---------------------------------------------------------------------------
#define C2LOG2E 2.8853900817779268f   // 2*log2(e)

__device__ __forceinline__ float tanh_term(float q, float kc, float w, float a) {
  float e = __builtin_amdgcn_exp2f(fmaf(q, C2LOG2E, kc));
  float r = __builtin_amdgcn_rcpf(e + 1.0f);
  return fmaf(w, fmaf(-2.0f, r, 1.0f), a);
}

__global__ __launch_bounds__(256) void score_kernel(
    const float* __restrict__ qp, const float* __restrict__ kpt,
    const float* __restrict__ wv, float* __restrict__ out)
{
  const int t  = threadIdx.x;
  const int b  = blockIdx.z;
  const int k  = blockIdx.x * 256 + t;
  const int q0 = blockIdx.y * 4;

  const float* __restrict__ qbase = qp + (b * 512 + q0) * HH;  // uniform rows
  const float* __restrict__ kbase = kpt + b * 512 + k;         // per-lane col

  float acc[4] = {0.f, 0.f, 0.f, 0.f};

  for (int h = 0; h < HH; h += 4) {
    float4 w4 = *(const float4*)(wv + h);                 // uniform -> s_load
    float kc0 = kbase[(h + 0) * MM] * C2LOG2E;            // coalesced dword
    float kc1 = kbase[(h + 1) * MM] * C2LOG2E;
    float kc2 = kbase[(h + 2) * MM] * C2LOG2E;
    float kc3 = kbase[(h + 3) * MM] * C2LOG2E;
#pragma unroll
    for (int qi = 0; qi < 4; ++qi) {
      float4 qv = *(const float4*)(qbase + qi * HH + h);  // uniform -> s_load
      acc[qi] = tanh_term(qv.x, kc0, w4.x, acc[qi]);
      acc[qi] = tanh_term(qv.y, kc1, w4.y, acc[qi]);
      acc[qi] = tanh_term(qv.z, kc2, w4.z, acc[qi]);
      acc[qi] = tanh_term(qv.w, kc3, w4.w, acc[qi]);
    }
  }

#pragma unroll
  for (int qi = 0; qi < 4; ++qi)
    out[(b * 512 + q0 + qi) * 512 + blockIdx.x * 256 + t] = acc[qi];
}

// ---------------------------------------------------------------------------
extern "C" void kernel_launch(void* const* d_in, const int* in_sizes, int n_in,
                              void* d_out, int out_size, void* d_ws, size_t ws_size,
                              hipStream_t stream) {
  (void)in_sizes; (void)n_in; (void)out_size; (void)ws_size;
  const float* queries = (const float*)d_in[0];  // (4,512,1,512)
  const float* keys    = (const float*)d_in[1];  // (4,1,512,512)
  const float* Wq      = (const float*)d_in[2];  // (512,256)
  const float* Wk      = (const float*)d_in[3];  // (512,256)
  const float* wv      = (const float*)d_in[4];  // (256,)
  float* out = (float*)d_out;                    // (4,512,512)

  float* qp  = (float*)d_ws;        // [2048][256] row-major, 2 MB
  float* kpt = qp + (size_t)MM * HH;// [256][2048] transposed, 2 MB

  proj_kernel<<<dim3(MM / 16, HH / 16, 2), 64, 0, stream>>>(
      queries, keys, Wq, Wk, qp, kpt);
  score_kernel<<<dim3(2, 128, 4), 256, 0, stream>>>(qp, kpt, wv, out);
}

// Round 2
// 139.378 us; speedup vs baseline: 1.0853x; 1.0853x over previous
//
#include <hip/hip_runtime.h>
#include <hip/hip_bf16.h>

// B=4, Q=K=512, D=512, H=256
#define HH 256
#define DD 512
#define MM 2048                       // B*Q == B*K flattened rows
#define CSCALE 2.8853900817779268f    // 2*log2(e), folded into W (linear)

typedef __bf16 bf16x8 __attribute__((ext_vector_type(8)));
typedef float floatx4 __attribute__((ext_vector_type(4)));

// ---------------------------------------------------------------------------
// prep: (a) transpose+scale Wq,Wk (512x256 f32) -> Wt[2][256][512] bf16
//       (b) wv2 = -2*wv, sumW = sum(wv)
// blocks 0..255: 32x32 LDS tile transpose (128 tiles per matrix)
// block 256:     wv reduction
// ---------------------------------------------------------------------------
__global__ __launch_bounds__(256) void prep_kernel(
    const float* __restrict__ Wq, const float* __restrict__ Wk,
    const float* __restrict__ wv,
    __bf16* __restrict__ Wt, float* __restrict__ wv2, float* __restrict__ sumWp)
{
  const int bx = blockIdx.x;
  if (bx < 256) {
    const int mat  = bx >> 7;
    const int tile = bx & 127;
    const int kt = tile & 15;    // 512/32 k-tiles
    const int nt = tile >> 4;    // 256/32 n-tiles
    const float* __restrict__ W = mat ? Wk : Wq;
    __bf16* __restrict__ Wo = Wt + (size_t)mat * HH * DD;
    __shared__ float lds[32][33];
    const int i = threadIdx.x >> 5;   // 0..7
    const int j = threadIdx.x & 31;   // 0..31
    const int k0 = kt * 32, n0 = nt * 32;
#pragma unroll
    for (int p = 0; p < 4; ++p)
      lds[i + p * 8][j] = W[(k0 + i + p * 8) * HH + n0 + j];
    __syncthreads();
#pragma unroll
    for (int p = 0; p < 4; ++p) {
      const int n = i + p * 8;
      Wo[(n0 + n) * DD + k0 + j] = (__bf16)(lds[j][n] * CSCALE);
    }
  } else {
    __shared__ float red[256];
    const int t = threadIdx.x;
    float w = wv[t];
    wv2[t] = -2.0f * w;
    red[t] = w;
    __syncthreads();
    for (int s = 128; s > 0; s >>= 1) {
      if (t < s) red[t] += red[t + s];
      __syncthreads();
    }
    if (t == 0) *sumWp = red[0];
  }
}

// ---------------------------------------------------------------------------
// proj: P = X(2048x512 f32) @ Wt^T (bf16, prescaled). 4 waves/block, each wave
// a 16x32 output tile (2 MFMA accs), block tile 32x64.
//   z==0: queries -> qp bf16 [2048][256] row-major
//   z==1: keys    -> kpt2 f32 [64][2048][4]  (h-quad packed for float4 loads)
// Fragment layouts (HW-verified in round 1):
//   A: lane holds A[m=lane&15][k=(lane>>4)*8+j]; B: B[k=(lane>>4)*8+j][n=lane&15]
//   D: reg i -> row=(lane>>4)*4+i, col=lane&15
// ---------------------------------------------------------------------------
__global__ __launch_bounds__(256) void proj_kernel(
    const float* __restrict__ queries, const float* __restrict__ keys,
    const __bf16* __restrict__ Wt,
    __bf16* __restrict__ qp, float* __restrict__ kpt2)
{
  const int w    = threadIdx.x >> 6;
  const int lane = threadIdx.x & 63;
  const int quad = lane >> 4;
  const int r    = lane & 15;
  const bool is_k = (blockIdx.z != 0);
  const float* __restrict__ X = is_k ? keys : queries;
  const __bf16* __restrict__ Wb = Wt + (is_k ? (size_t)HH * DD : 0);

  const int m0 = blockIdx.x * 32 + (w >> 1) * 16;
  const int n0 = blockIdx.y * 64 + (w & 1) * 32;

  floatx4 acc0 = {0.f, 0.f, 0.f, 0.f};
  floatx4 acc1 = {0.f, 0.f, 0.f, 0.f};
  const float* arow = X + (size_t)(m0 + r) * DD + quad * 8;
  const __bf16* b0 = Wb + (size_t)(n0 + r) * DD + quad * 8;
  const __bf16* b1 = b0 + 16 * DD;

  for (int kk = 0; kk < DD; kk += 32) {
    float4 a0 = *(const float4*)(arow + kk);
    float4 a1 = *(const float4*)(arow + kk + 4);
    bf16x8 af;
    af[0] = (__bf16)a0.x; af[1] = (__bf16)a0.y;
    af[2] = (__bf16)a0.z; af[3] = (__bf16)a0.w;
    af[4] = (__bf16)a1.x; af[5] = (__bf16)a1.y;
    af[6] = (__bf16)a1.z; af[7] = (__bf16)a1.w;
    bf16x8 bf0 = *(const bf16x8*)(b0 + kk);
    bf16x8 bf1 = *(const bf16x8*)(b1 + kk);
    acc0 = __builtin_amdgcn_mfma_f32_16x16x32_bf16(af, bf0, acc0, 0, 0, 0);
    acc1 = __builtin_amdgcn_mfma_f32_16x16x32_bf16(af, bf1, acc1, 0, 0, 0);
  }

  const int mrow = m0 + quad * 4;
  if (!is_k) {
#pragma unroll
    for (int i = 0; i < 4; ++i) {
      qp[(size_t)(mrow + i) * HH + n0 + r]      = (__bf16)acc0[i];
      qp[(size_t)(mrow + i) * HH + n0 + 16 + r] = (__bf16)acc1[i];
    }
  } else {
#pragma unroll
    for (int i = 0; i < 4; ++i) {
      int na = n0 + r, nb = n0 + 16 + r;
      kpt2[((size_t)(na >> 2) * MM + (mrow + i)) * 4 + (na & 3)] = acc0[i];
      kpt2[((size_t)(nb >> 2) * MM + (mrow + i)) * 4 + (nb & 3)] = acc1[i];
    }
  }
}

// ---------------------------------------------------------------------------
// score: out[b,q,k] = sumW + sum_h (-2*wv[h]) * rcp(exp2(qc+kc) + 1)
// (== sum_h wv[h]*tanh(q+k), since qc,kc prescaled by 2*log2e)
// thread -> one k, TQ=2 q rows. One float4 load per 4-h step; q/wv uniform
// (scalar path). grid (2,256,4)=2048 blocks = 8 blocks/CU -> 100% occ cap.
// ---------------------------------------------------------------------------
__device__ __forceinline__ float term(float y, float w, float a) {
  float e = __builtin_amdgcn_exp2f(y);
  return fmaf(w, __builtin_amdgcn_rcpf(e + 1.0f), a);
}

__global__ __launch_bounds__(256) void score_kernel(
    const __bf16* __restrict__ qp, const float4* __restrict__ kpt2,
    const float* __restrict__ wv2, const float* __restrict__ sumWp,
    float* __restrict__ out)
{
  const int t  = threadIdx.x;
  const int b  = blockIdx.z;
  const int k  = blockIdx.x * 256 + t;
  const int q0 = blockIdx.y * 2;
  const float sumW = *sumWp;

  const float4* __restrict__ kptr = kpt2 + (size_t)b * 512 + k;
  const unsigned* __restrict__ qrow0 =
      (const unsigned*)(qp + (size_t)(b * 512 + q0) * HH);
  const unsigned* __restrict__ qrow1 =
      (const unsigned*)(qp + (size_t)(b * 512 + q0 + 1) * HH);

  float acc0 = 0.f, acc1 = 0.f;

  for (int hq = 0; hq < 64; ++hq) {
    float4 kc = kptr[(size_t)hq * MM];
    float4 w4 = *(const float4*)(wv2 + hq * 4);
    unsigned pa0 = qrow0[hq * 2], pb0 = qrow0[hq * 2 + 1];
    unsigned pa1 = qrow1[hq * 2], pb1 = qrow1[hq * 2 + 1];
    float q00 = __uint_as_float(pa0 << 16);
    float q01 = __uint_as_float(pa0 & 0xffff0000u);
    float q02 = __uint_as_float(pb0 << 16);
    float q03 = __uint_as_float(pb0 & 0xffff0000u);
    float q10 = __uint_as_float(pa1 << 16);
    float q11 = __uint_as_float(pa1 & 0xffff0000u);
    float q12 = __uint_as_float(pb1 << 16);
    float q13 = __uint_as_float(pb1 & 0xffff0000u);
    acc0 = term(q00 + kc.x, w4.x, acc0);
    acc0 = term(q01 + kc.y, w4.y, acc0);
    acc0 = term(q02 + kc.z, w4.z, acc0);
    acc0 = term(q03 + kc.w, w4.w, acc0);
    acc1 = term(q10 + kc.x, w4.x, acc1);
    acc1 = term(q11 + kc.y, w4.y, acc1);
    acc1 = term(q12 + kc.z, w4.z, acc1);
    acc1 = term(q13 + kc.w, w4.w, acc1);
  }

  const size_t obase = ((size_t)b * 512 + q0) * 512 + blockIdx.x * 256 + t;
  out[obase]       = sumW + acc0;
  out[obase + 512] = sumW + acc1;
}

// ---------------------------------------------------------------------------
extern "C" void kernel_launch(void* const* d_in, const int* in_sizes, int n_in,
                              void* d_out, int out_size, void* d_ws, size_t ws_size,
                              hipStream_t stream) {
  (void)in_sizes; (void)n_in; (void)out_size; (void)ws_size;
  const float* queries = (const float*)d_in[0];
  const float* keys    = (const float*)d_in[1];
  const float* Wq      = (const float*)d_in[2];
  const float* Wk      = (const float*)d_in[3];
  const float* wv      = (const float*)d_in[4];
  float* out = (float*)d_out;

  // ws layout (<= 4 MB, proven budget):
  //   [0, 512K)        Wt   bf16 [2][256][512]
  //   [512K, 513K)     wv2  f32 [256]
  //   [513K, 513K+4)   sumW f32
  //   [1M, 2M)         qp   bf16 [2048][256]
  //   [2M, 4M)         kpt2 f32  [64][2048][4]
  char* ws = (char*)d_ws;
  __bf16* Wt    = (__bf16*)ws;
  float*  wv2   = (float*)(ws + (512 << 10));
  float*  sumWp = (float*)(ws + (513 << 10));
  __bf16* qp    = (__bf16*)(ws + (1 << 20));
  float*  kpt2  = (float*)(ws + (2 << 20));

  prep_kernel<<<dim3(257), 256, 0, stream>>>(Wq, Wk, wv, Wt, wv2, sumWp);
  proj_kernel<<<dim3(64, 4, 2), 256, 0, stream>>>(queries, keys, Wt, qp, kpt2);
  score_kernel<<<dim3(2, 256, 4), 256, 0, stream>>>(
      qp, (const float4*)kpt2, wv2, sumWp, out);
}

// Round 3
// 115.467 us; speedup vs baseline: 1.3100x; 1.2071x over previous
//
#include <hip/hip_runtime.h>
#include <hip/hip_bf16.h>

// B=4, Q=K=512, D=512, H=256
#define HH 256
#define DD 512
#define MM 2048                       // B*Q == B*K flattened rows
#define CSCALE 2.8853900817779268f    // 2*log2(e), folded into W (linear)

typedef __bf16 bf16x8 __attribute__((ext_vector_type(8)));
typedef float floatx4 __attribute__((ext_vector_type(4)));

// ---------------------------------------------------------------------------
// prep: (a) transpose+scale Wq,Wk (512x256 f32) -> Wt[2][256][512] bf16
//       (b) wv2 = -2*wv, sumW = sum(wv)
// ---------------------------------------------------------------------------
__global__ __launch_bounds__(256) void prep_kernel(
    const float* __restrict__ Wq, const float* __restrict__ Wk,
    const float* __restrict__ wv,
    __bf16* __restrict__ Wt, float* __restrict__ wv2, float* __restrict__ sumWp)
{
  const int bx = blockIdx.x;
  if (bx < 256) {
    const int mat  = bx >> 7;
    const int tile = bx & 127;
    const int kt = tile & 15;    // 512/32 k-tiles
    const int nt = tile >> 4;    // 256/32 n-tiles
    const float* __restrict__ W = mat ? Wk : Wq;
    __bf16* __restrict__ Wo = Wt + (size_t)mat * HH * DD;
    __shared__ float lds[32][33];
    const int i = threadIdx.x >> 5;   // 0..7
    const int j = threadIdx.x & 31;   // 0..31
    const int k0 = kt * 32, n0 = nt * 32;
#pragma unroll
    for (int p = 0; p < 4; ++p)
      lds[i + p * 8][j] = W[(k0 + i + p * 8) * HH + n0 + j];
    __syncthreads();
#pragma unroll
    for (int p = 0; p < 4; ++p) {
      const int n = i + p * 8;
      Wo[(n0 + n) * DD + k0 + j] = (__bf16)(lds[j][n] * CSCALE);
    }
  } else {
    __shared__ float red[256];
    const int t = threadIdx.x;
    float w = wv[t];
    wv2[t] = -2.0f * w;
    red[t] = w;
    __syncthreads();
    for (int s = 128; s > 0; s >>= 1) {
      if (t < s) red[t] += red[t + s];
      __syncthreads();
    }
    if (t == 0) *sumWp = red[0];
  }
}

// ---------------------------------------------------------------------------
// proj: P = X(2048x512 f32) @ Wt^T (bf16, prescaled by 2*log2e).
// Epilogue applies exp2:
//   z==0: queries -> eq = exp2(qc) as bf16 [2048][256] row-major
//   z==1: keys    -> ek = exp2(kc) as f32  [64][2048][4] (h-quad packed)
// Fragment layouts (HW-verified rounds 1-2):
//   A: lane A[m=lane&15][k=(lane>>4)*8+j]; B: B[k=(lane>>4)*8+j][n=lane&15]
//   D: reg i -> row=(lane>>4)*4+i, col=lane&15
// ---------------------------------------------------------------------------
__global__ __launch_bounds__(256) void proj_kernel(
    const float* __restrict__ queries, const float* __restrict__ keys,
    const __bf16* __restrict__ Wt,
    __bf16* __restrict__ eqp, float* __restrict__ ekp)
{
  const int w    = threadIdx.x >> 6;
  const int lane = threadIdx.x & 63;
  const int quad = lane >> 4;
  const int r    = lane & 15;
  const bool is_k = (blockIdx.z != 0);
  const float* __restrict__ X = is_k ? keys : queries;
  const __bf16* __restrict__ Wb = Wt + (is_k ? (size_t)HH * DD : 0);

  const int m0 = blockIdx.x * 32 + (w >> 1) * 16;
  const int n0 = blockIdx.y * 64 + (w & 1) * 32;

  floatx4 acc0 = {0.f, 0.f, 0.f, 0.f};
  floatx4 acc1 = {0.f, 0.f, 0.f, 0.f};
  const float* arow = X + (size_t)(m0 + r) * DD + quad * 8;
  const __bf16* b0 = Wb + (size_t)(n0 + r) * DD + quad * 8;
  const __bf16* b1 = b0 + 16 * DD;

  for (int kk = 0; kk < DD; kk += 32) {
    float4 a0 = *(const float4*)(arow + kk);
    float4 a1 = *(const float4*)(arow + kk + 4);
    bf16x8 af;
    af[0] = (__bf16)a0.x; af[1] = (__bf16)a0.y;
    af[2] = (__bf16)a0.z; af[3] = (__bf16)a0.w;
    af[4] = (__bf16)a1.x; af[5] = (__bf16)a1.y;
    af[6] = (__bf16)a1.z; af[7] = (__bf16)a1.w;
    bf16x8 bf0 = *(const bf16x8*)(b0 + kk);
    bf16x8 bf1 = *(const bf16x8*)(b1 + kk);
    acc0 = __builtin_amdgcn_mfma_f32_16x16x32_bf16(af, bf0, acc0, 0, 0, 0);
    acc1 = __builtin_amdgcn_mfma_f32_16x16x32_bf16(af, bf1, acc1, 0, 0, 0);
  }

  const int mrow = m0 + quad * 4;
  if (!is_k) {
#pragma unroll
    for (int i = 0; i < 4; ++i) {
      eqp[(size_t)(mrow + i) * HH + n0 + r] =
          (__bf16)__builtin_amdgcn_exp2f(acc0[i]);
      eqp[(size_t)(mrow + i) * HH + n0 + 16 + r] =
          (__bf16)__builtin_amdgcn_exp2f(acc1[i]);
    }
  } else {
#pragma unroll
    for (int i = 0; i < 4; ++i) {
      int na = n0 + r, nb = n0 + 16 + r;
      ekp[((size_t)(na >> 2) * MM + (mrow + i)) * 4 + (na & 3)] =
          __builtin_amdgcn_exp2f(acc0[i]);
      ekp[((size_t)(nb >> 2) * MM + (mrow + i)) * 4 + (nb & 3)] =
          __builtin_amdgcn_exp2f(acc1[i]);
    }
  }
}

// ---------------------------------------------------------------------------
// score: out[b,q,k] = sumW + sum_h wv2[h] * rcp(fma(eq[q,h], ek[k,h], 1))
// (== sum_h wv[h]*tanh(q+k): exp2(qc+kc) factored into eq*ek, wv2 = -2*wv)
// Per term: 1 fma + 1 rcp + 1 fma = 2 VALU + 1 trans = ~12 issue-cyc/wave-term.
// q-side (eq bf16) and wv2 are wave-uniform -> SMEM + SALU unpack (free pipe).
// ek reads: one coalesced dwordx4 per 4h per lane.
// grid (2,256,4)=2048 blocks, TQ=2.
// ---------------------------------------------------------------------------
__global__ __launch_bounds__(256) void score_kernel(
    const __bf16* __restrict__ eqp, const float4* __restrict__ ekp,
    const float* __restrict__ wv2, const float* __restrict__ sumWp,
    float* __restrict__ out)
{
  const int t  = threadIdx.x;
  const int b  = blockIdx.z;
  const int k  = blockIdx.x * 256 + t;
  const int q0 = blockIdx.y * 2;
  const float sumW = *sumWp;

  const float4* __restrict__ kptr = ekp + (size_t)b * 512 + k;
  const unsigned* __restrict__ qrow0 =
      (const unsigned*)(eqp + (size_t)(b * 512 + q0) * HH);
  const unsigned* __restrict__ qrow1 =
      (const unsigned*)(eqp + (size_t)(b * 512 + q0 + 1) * HH);

  float acc0 = 0.f, acc1 = 0.f;

#pragma unroll 8
  for (int hq = 0; hq < 64; ++hq) {
    float4 ek = kptr[(size_t)hq * MM];
    float4 w4 = *(const float4*)(wv2 + hq * 4);
    unsigned pa0 = qrow0[hq * 2], pb0 = qrow0[hq * 2 + 1];
    unsigned pa1 = qrow1[hq * 2], pb1 = qrow1[hq * 2 + 1];
    float q00 = __uint_as_float(pa0 << 16);
    float q01 = __uint_as_float(pa0 & 0xffff0000u);
    float q02 = __uint_as_float(pb0 << 16);
    float q03 = __uint_as_float(pb0 & 0xffff0000u);
    float q10 = __uint_as_float(pa1 << 16);
    float q11 = __uint_as_float(pa1 & 0xffff0000u);
    float q12 = __uint_as_float(pb1 << 16);
    float q13 = __uint_as_float(pb1 & 0xffff0000u);
    acc0 = fmaf(w4.x, __builtin_amdgcn_rcpf(fmaf(q00, ek.x, 1.0f)), acc0);
    acc0 = fmaf(w4.y, __builtin_amdgcn_rcpf(fmaf(q01, ek.y, 1.0f)), acc0);
    acc0 = fmaf(w4.z, __builtin_amdgcn_rcpf(fmaf(q02, ek.z, 1.0f)), acc0);
    acc0 = fmaf(w4.w, __builtin_amdgcn_rcpf(fmaf(q03, ek.w, 1.0f)), acc0);
    acc1 = fmaf(w4.x, __builtin_amdgcn_rcpf(fmaf(q10, ek.x, 1.0f)), acc1);
    acc1 = fmaf(w4.y, __builtin_amdgcn_rcpf(fmaf(q11, ek.y, 1.0f)), acc1);
    acc1 = fmaf(w4.z, __builtin_amdgcn_rcpf(fmaf(q12, ek.z, 1.0f)), acc1);
    acc1 = fmaf(w4.w, __builtin_amdgcn_rcpf(fmaf(q13, ek.w, 1.0f)), acc1);
  }

  const size_t obase = ((size_t)b * 512 + q0) * 512 + blockIdx.x * 256 + t;
  out[obase]       = sumW + acc0;
  out[obase + 512] = sumW + acc1;
}

// ---------------------------------------------------------------------------
extern "C" void kernel_launch(void* const* d_in, const int* in_sizes, int n_in,
                              void* d_out, int out_size, void* d_ws, size_t ws_size,
                              hipStream_t stream) {
  (void)in_sizes; (void)n_in; (void)out_size; (void)ws_size;
  const float* queries = (const float*)d_in[0];
  const float* keys    = (const float*)d_in[1];
  const float* Wq      = (const float*)d_in[2];
  const float* Wk      = (const float*)d_in[3];
  const float* wv      = (const float*)d_in[4];
  float* out = (float*)d_out;

  // ws layout (3.5 MB of the proven 4 MB budget):
  //   [0, 512K)        Wt   bf16 [2][256][512]
  //   [512K, 513K)     wv2  f32 [256] ; sumW at 513K
  //   [1M, 2M)         eq   bf16 [2048][256]   (exp2 of scaled q-proj)
  //   [2M, 4M)         ek   f32  [64][2048][4] (exp2 of scaled k-proj, h-quads)
  char* ws = (char*)d_ws;
  __bf16* Wt    = (__bf16*)ws;
  float*  wv2   = (float*)(ws + (512 << 10));
  float*  sumWp = (float*)(ws + (513 << 10));
  __bf16* eqp   = (__bf16*)(ws + (1 << 20));
  float*  ekp   = (float*)(ws + (2 << 20));

  prep_kernel<<<dim3(257), 256, 0, stream>>>(Wq, Wk, wv, Wt, wv2, sumWp);
  proj_kernel<<<dim3(64, 4, 2), 256, 0, stream>>>(queries, keys, Wt, eqp, ekp);
  score_kernel<<<dim3(2, 256, 4), 256, 0, stream>>>(
      eqp, (const float4*)ekp, wv2, sumWp, out);
}